// Round 2
// baseline (505.388 us; speedup 1.0000x reference)
//
#include <hip/hip_runtime.h>
#include <math.h>

#define N_NODES 100000
#define N_EDGES 1600000
#define NBUCK 391          // ceil(100000 / 256)
#define BSTRIDE 4608       // bucket slack stride: mean 4096 + 8 sigma

typedef __attribute__((ext_vector_type(8))) _Float16 h8v;
typedef __attribute__((ext_vector_type(4))) float f32x4;

// h buffers use a feature-blocked layout: [8 col-blocks][N_NODES+1 rows][16 fp16]
// so each 32B row-slice of one col-block is an independent 3.2MB region that
// fits a single XCD's 4MB L2. Aggregation assigns col-block = blockIdx&7 so
// round-robin dispatch pins each slice to one XCD (T1 mapping).

// ---------------- CSR build: 2 kernels + 1 memset ----------------

__launch_bounds__(256)
__global__ void k_bpart(const int* __restrict__ srcv, const int* __restrict__ dstv,
                        int* __restrict__ bcnt, unsigned int* __restrict__ ebuf) {
    __shared__ int hist[NBUCK];
    __shared__ int cur[NBUCK];
    const int tid = threadIdx.x;
    for (int t = tid; t < NBUCK; t += 256) hist[t] = 0;
    __syncthreads();
    const int base = blockIdx.x * 4096;
#pragma unroll
    for (int i = 0; i < 16; i++) {
        int e = base + i * 256 + tid;
        if (e < N_EDGES) atomicAdd(&hist[dstv[e] >> 8], 1);
    }
    __syncthreads();
    for (int t = tid; t < NBUCK; t += 256)
        if (hist[t]) cur[t] = t * BSTRIDE + atomicAdd(&bcnt[t], hist[t]);
    __syncthreads();
#pragma unroll
    for (int i = 0; i < 16; i++) {
        int e = base + i * 256 + tid;
        if (e < N_EDGES) {
            int d = dstv[e];
            int p = atomicAdd(&cur[d >> 8], 1);
            ebuf[p] = ((unsigned int)srcv[e] << 8) | (unsigned int)(d & 255);
        }
    }
}

__launch_bounds__(256)
__global__ void k_bucket(const unsigned int* __restrict__ ebuf, const int* __restrict__ bcnt,
                         int2* __restrict__ rowse, float* __restrict__ dinv,
                         int* __restrict__ colidx) {
    __shared__ int cnt[256];
    __shared__ int s[256];
    __shared__ int cur[256];
    const int tid = threadIdx.x;
    const int b = blockIdx.x;
    const int e0 = b * BSTRIDE;
    const int e1 = e0 + bcnt[b];
    cnt[tid] = 0;
    __syncthreads();
    for (int e = e0 + tid; e < e1; e += 256) atomicAdd(&cnt[ebuf[e] & 255u], 1);
    __syncthreads();
    int v = cnt[tid];
    int x = v;
    s[tid] = x;
    __syncthreads();
    for (int d = 1; d < 256; d <<= 1) {
        int t = (tid >= d) ? s[tid - d] : 0;
        __syncthreads();
        x += t;
        s[tid] = x;
        __syncthreads();
    }
    int start = e0 + x - v;
    int node = b * 256 + tid;
    if (node < N_NODES) {
        rowse[node] = make_int2(start, start + v);
        dinv[node] = rsqrtf((float)(v + 1));  // +1 self-loop
    }
    cur[tid] = start;
    __syncthreads();
    for (int e = e0 + tid; e < e1; e += 256) {
        unsigned int sd = ebuf[e];
        int pos = atomicAdd(&cur[sd & 255u], 1);
        colidx[pos] = (int)(sd >> 8);
    }
}

// Zero the sentinel rows (index N_NODES) of the gather buffers.
__global__ void k_zrows(_Float16* __restrict__ bufA, _Float16* __restrict__ zbuf) {
    int t = threadIdx.x;
    if (t < 128) {
        // blocked layout: block t>>4, element t&15 of sentinel row
        bufA[((size_t)(t >> 4) * (N_NODES + 1) + N_NODES) * 16 + (t & 15)] = (_Float16)0.f;
    }
    if (t < 64)  zbuf[(size_t)N_NODES * 64 + t] = (_Float16)0.f;
}

// ---------------- fused weight prep ----------------

__global__ void k_wprep_all(const float* __restrict__ W1, const float* __restrict__ W2,
                            const float* __restrict__ W3, _Float16* __restrict__ Wt) {
    int idx = blockIdx.x * blockDim.x + threadIdx.x;
    if (idx >= 304 * 128) return;
    int n = idx / 128, k = idx % 128;
    const float* W;
    int ncols, nloc;
    _Float16 *ph, *pl;
    if (n < 128)      { W = W1; ncols = 128; nloc = n;       ph = Wt;                 pl = Wt + 128 * 128; }
    else if (n < 256) { W = W2; ncols = 128; nloc = n - 128; ph = Wt + 2 * 128 * 128; pl = Wt + 3 * 128 * 128; }
    else              { W = W3; ncols = 40;  nloc = n - 256; ph = Wt + 4 * 128 * 128; pl = Wt + 4 * 128 * 128 + 48 * 128; }
    float v = (nloc < ncols) ? W[k * ncols + nloc] : 0.f;
    _Float16 hi = (_Float16)v;
    _Float16 lo = (_Float16)(v - (float)hi);
    ph[nloc * 128 + k] = hi;
    pl[nloc * 128 + k] = lo;
}

// ---------------- Persistent-B MFMA GEMMs ----------------
// B fragments (hi+lo, 64 VGPRs) loaded ONCE per wave; grid-stride loop over
// 32-row tiles. 625 blocks x 5 tiles = 3125 tiles exactly.
// Outputs (and fp16 A-inputs) use the feature-blocked layout.

#define GEMM_GRID 625
#define NTILES 3125

__launch_bounds__(256, 2)
__global__ void k_gemm128_f32(const float* __restrict__ Af,
                              const _Float16* __restrict__ Wthi, const _Float16* __restrict__ Wtlo,
                              const float* __restrict__ dinv, _Float16* __restrict__ out) {
    const int lane = threadIdx.x & 63;
    const int wi = threadIdx.x >> 6;
    const int nb = wi * 32;
    const int nn = lane & 15;
    const int kq = (lane >> 4) * 8;
    const int quad = lane >> 4;

    h8v bh[4][2], bl[4][2];
#pragma unroll
    for (int c = 0; c < 4; c++)
#pragma unroll
        for (int t = 0; t < 2; t++) {
            int off = (nb + t * 16 + nn) * 128 + c * 32 + kq;
            bh[c][t] = *(const h8v*)(Wthi + off);
            bl[c][t] = *(const h8v*)(Wtlo + off);
        }

    for (int rt = blockIdx.x; rt < NTILES; rt += GEMM_GRID) {
        const int r0 = rt * 32;
        f32x4 acc[2][2] = {};
#pragma unroll
        for (int c = 0; c < 4; c++) {
            h8v a[2];
#pragma unroll
            for (int m = 0; m < 2; m++) {
                const float* p = Af + (size_t)(r0 + m * 16 + nn) * 128 + c * 32 + kq;
                float4 p0 = *(const float4*)p;
                float4 p1 = *(const float4*)(p + 4);
                h8v av = {(_Float16)p0.x, (_Float16)p0.y, (_Float16)p0.z, (_Float16)p0.w,
                          (_Float16)p1.x, (_Float16)p1.y, (_Float16)p1.z, (_Float16)p1.w};
                a[m] = av;
            }
#pragma unroll
            for (int m = 0; m < 2; m++)
#pragma unroll
                for (int t = 0; t < 2; t++) {
                    acc[m][t] = __builtin_amdgcn_mfma_f32_16x16x32_f16(a[m], bh[c][t], acc[m][t], 0, 0, 0);
                    acc[m][t] = __builtin_amdgcn_mfma_f32_16x16x32_f16(a[m], bl[c][t], acc[m][t], 0, 0, 0);
                }
        }
#pragma unroll
        for (int m = 0; m < 2; m++)
#pragma unroll
            for (int reg = 0; reg < 4; reg++) {
                int r = r0 + m * 16 + quad * 4 + reg;
                float dv = dinv[r];
#pragma unroll
                for (int t = 0; t < 2; t++) {
                    int blk = (nb >> 4) + t;
                    out[((size_t)blk * (N_NODES + 1) + r) * 16 + nn] = (_Float16)(acc[m][t][reg] * dv);
                }
            }
    }
}

__launch_bounds__(256, 2)
__global__ void k_gemm128(const _Float16* __restrict__ A,
                          const _Float16* __restrict__ Wthi, const _Float16* __restrict__ Wtlo,
                          const float* __restrict__ dinv, _Float16* __restrict__ out) {
    const int lane = threadIdx.x & 63;
    const int wi = threadIdx.x >> 6;
    const int nb = wi * 32;
    const int nn = lane & 15;
    const int kq = (lane >> 4) * 8;
    const int quad = lane >> 4;

    h8v bh[4][2], bl[4][2];
#pragma unroll
    for (int c = 0; c < 4; c++)
#pragma unroll
        for (int t = 0; t < 2; t++) {
            int off = (nb + t * 16 + nn) * 128 + c * 32 + kq;
            bh[c][t] = *(const h8v*)(Wthi + off);
            bl[c][t] = *(const h8v*)(Wtlo + off);
        }

    for (int rt = blockIdx.x; rt < NTILES; rt += GEMM_GRID) {
        const int r0 = rt * 32;
        f32x4 acc[2][2] = {};
#pragma unroll
        for (int c = 0; c < 4; c++) {
            h8v a[2];
#pragma unroll
            for (int m = 0; m < 2; m++) {
                int blk = 2 * c + (kq >> 4);
                a[m] = *(const h8v*)(A + ((size_t)blk * (N_NODES + 1) + (r0 + m * 16 + nn)) * 16 + (kq & 8));
            }
#pragma unroll
            for (int m = 0; m < 2; m++)
#pragma unroll
                for (int t = 0; t < 2; t++) {
                    acc[m][t] = __builtin_amdgcn_mfma_f32_16x16x32_f16(a[m], bh[c][t], acc[m][t], 0, 0, 0);
                    acc[m][t] = __builtin_amdgcn_mfma_f32_16x16x32_f16(a[m], bl[c][t], acc[m][t], 0, 0, 0);
                }
        }
#pragma unroll
        for (int m = 0; m < 2; m++)
#pragma unroll
            for (int reg = 0; reg < 4; reg++) {
                int r = r0 + m * 16 + quad * 4 + reg;
                float dv = dinv[r];
#pragma unroll
                for (int t = 0; t < 2; t++) {
                    int blk = (nb >> 4) + t;
                    out[((size_t)blk * (N_NODES + 1) + r) * 16 + nn] = (_Float16)(acc[m][t][reg] * dv);
                }
            }
    }
}

// Layer-3 GEMM: 40 real cols (48 written) into [N+1][64]-stride buffer.
// A is feature-blocked; output row-major 64-stride (for agg_out).
#define G40_GRID 160

__launch_bounds__(256, 2)
__global__ void k_gemm40(const _Float16* __restrict__ A,
                         const _Float16* __restrict__ Wthi, const _Float16* __restrict__ Wtlo,
                         const float* __restrict__ dinv, _Float16* __restrict__ out) {
    const int lane = threadIdx.x & 63;
    const int wi = threadIdx.x >> 6;
    const int nn = lane & 15;
    const int kq = (lane >> 4) * 8;
    const int quad = lane >> 4;

    h8v bh[4][3], bl[4][3];
#pragma unroll
    for (int c = 0; c < 4; c++)
#pragma unroll
        for (int t = 0; t < 3; t++) {
            int off = (t * 16 + nn) * 128 + c * 32 + kq;
            bh[c][t] = *(const h8v*)(Wthi + off);
            bl[c][t] = *(const h8v*)(Wtlo + off);
        }

    for (int rt = blockIdx.x * 4 + wi; rt < NTILES; rt += G40_GRID * 4) {
        const int r0 = rt * 32;
        f32x4 acc[2][3] = {};
#pragma unroll
        for (int c = 0; c < 4; c++) {
            h8v a[2];
#pragma unroll
            for (int m = 0; m < 2; m++) {
                int blk = 2 * c + (kq >> 4);
                a[m] = *(const h8v*)(A + ((size_t)blk * (N_NODES + 1) + (r0 + m * 16 + nn)) * 16 + (kq & 8));
            }
#pragma unroll
            for (int m = 0; m < 2; m++)
#pragma unroll
                for (int t = 0; t < 3; t++) {
                    acc[m][t] = __builtin_amdgcn_mfma_f32_16x16x32_f16(a[m], bh[c][t], acc[m][t], 0, 0, 0);
                    acc[m][t] = __builtin_amdgcn_mfma_f32_16x16x32_f16(a[m], bl[c][t], acc[m][t], 0, 0, 0);
                }
        }
#pragma unroll
        for (int m = 0; m < 2; m++)
#pragma unroll
            for (int reg = 0; reg < 4; reg++) {
                int r = r0 + m * 16 + quad * 4 + reg;
                float dv = dinv[r];
#pragma unroll
                for (int t = 0; t < 3; t++)
                    out[(size_t)r * 64 + t * 16 + nn] = (_Float16)(acc[m][t][reg] * dv);
            }
    }
}

// ---------------- Feature-blocked, XCD-affine aggregation (F=128) ----------------
// Each block handles col-block c = blockIdx&7 (-> one XCD via round-robin
// dispatch) over a 128-dst tile. The 3.2MB h-slice for c stays resident in
// that XCD's 4MB L2, so random row gathers hit L2 instead of the L3 fill path.
// Wave: 32 dst slots x 2 lane-parts (16B each -> 32B row per slot).

__launch_bounds__(256)
__global__ void k_agg4(const _Float16* __restrict__ hp, const int2* __restrict__ rowse,
                       const int* __restrict__ colidx, const float* __restrict__ bias,
                       _Float16* __restrict__ outp) {
    const int lane = threadIdx.x & 63;
    const int wi = threadIdx.x >> 6;
    const int c = blockIdx.x & 7;       // col-block == XCD slot
    const int tile = blockIdx.x >> 3;
    const int rs = lane >> 1;           // dst slot 0..31
    const int cp = lane & 1;            // 16B part within 32B row
    const int r = tile * 128 + wi * 32 + rs;

    int2 se = make_int2(0, 0);
    if (r < N_NODES) se = rowse[r];
    const int deg = se.y - se.x;
    int m = deg;
    m = max(m, __shfl_xor(m, 2));
    m = max(m, __shfl_xor(m, 4));
    m = max(m, __shfl_xor(m, 8));
    m = max(m, __shfl_xor(m, 16));
    m = max(m, __shfl_xor(m, 32));

    const _Float16* hpc = hp + ((size_t)c * (N_NODES + 1)) * 16 + cp * 8;
    h8v acc = {};
    for (int it = 0; it < m; it += 4) {
        int i0 = se.x + it;
        int s0 = __builtin_nontemporal_load(colidx + i0);
        int s1 = __builtin_nontemporal_load(colidx + i0 + 1);
        int s2 = __builtin_nontemporal_load(colidx + i0 + 2);
        int s3 = __builtin_nontemporal_load(colidx + i0 + 3);
        s0 = (it < deg) ? s0 : N_NODES;
        s1 = (it + 1 < deg) ? s1 : N_NODES;
        s2 = (it + 2 < deg) ? s2 : N_NODES;
        s3 = (it + 3 < deg) ? s3 : N_NODES;
        h8v v0 = *(const h8v*)(hpc + (size_t)s0 * 16);
        h8v v1 = *(const h8v*)(hpc + (size_t)s1 * 16);
        h8v v2 = *(const h8v*)(hpc + (size_t)s2 * 16);
        h8v v3 = *(const h8v*)(hpc + (size_t)s3 * 16);
        acc += v0;
        acc += v1;
        acc += v2;
        acc += v3;
    }

    if (r < N_NODES) {
        h8v sv = *(const h8v*)(hpc + (size_t)r * 16);  // self-loop
        float dv = rsqrtf((float)(deg + 1));
        const float* bp = bias + c * 16 + cp * 8;
        float4 b0 = *(const float4*)bp;
        float4 b1 = *(const float4*)(bp + 4);
        float bb[8] = {b0.x, b0.y, b0.z, b0.w, b1.x, b1.y, b1.z, b1.w};
        h8v o;
#pragma unroll
        for (int j = 0; j < 8; j++) {
            float sx = (float)acc[j] + (float)sv[j];
            o[j] = (_Float16)fmaxf(fmaf(dv, sx, bb[j]), 0.f);
        }
        *(h8v*)(outp + ((size_t)c * (N_NODES + 1) + r) * 16 + cp * 8) = o;
    }
}

// ---------------- Final aggregation (64-stride rows) + fused log_softmax ----------------

__launch_bounds__(256)
__global__ void k_agg_out(const _Float16* __restrict__ hp, const int2* __restrict__ rowse,
                          const int* __restrict__ colidx, float* __restrict__ out) {
    const int lane = threadIdx.x & 63;
    const int wid = (blockIdx.x * blockDim.x + threadIdx.x) >> 6;
    const int rs = lane >> 3;   // row slot 0..7
    const int cp = lane & 7;    // 16B col part
    const int r = wid * 8 + rs;

    const int2 se = rowse[r];
    const int deg = se.y - se.x;
    int m = deg;
    m = max(m, __shfl_xor(m, 8));
    m = max(m, __shfl_xor(m, 16));
    m = max(m, __shfl_xor(m, 32));

    const _Float16* hpc = hp + cp * 8;
    h8v acc = {};
    for (int it = 0; it < m; it += 4) {
        int i0 = se.x + it;
        int s0 = colidx[i0];
        int s1 = colidx[i0 + 1];
        int s2 = colidx[i0 + 2];
        int s3 = colidx[i0 + 3];
        s0 = (it < deg) ? s0 : N_NODES;
        s1 = (it + 1 < deg) ? s1 : N_NODES;
        s2 = (it + 2 < deg) ? s2 : N_NODES;
        s3 = (it + 3 < deg) ? s3 : N_NODES;
        h8v v0 = *(const h8v*)(hpc + (size_t)s0 * 64);
        h8v v1 = *(const h8v*)(hpc + (size_t)s1 * 64);
        h8v v2 = *(const h8v*)(hpc + (size_t)s2 * 64);
        h8v v3 = *(const h8v*)(hpc + (size_t)s3 * 64);
        acc += v0;
        acc += v1;
        acc += v2;
        acc += v3;
    }

    h8v sv = *(const h8v*)(hpc + (size_t)r * 64);  // self-loop
    float dv = rsqrtf((float)(deg + 1));
    float z[8];
#pragma unroll
    for (int j = 0; j < 8; j++) z[j] = dv * ((float)acc[j] + (float)sv[j]);

    const bool act = cp < 5;  // cols 0..39
    float pm = -INFINITY;
    if (act) {
#pragma unroll
        for (int j = 0; j < 8; j++) pm = fmaxf(pm, z[j]);
    }
    pm = fmaxf(pm, __shfl_xor(pm, 1));
    pm = fmaxf(pm, __shfl_xor(pm, 2));
    pm = fmaxf(pm, __shfl_xor(pm, 4));
    float pe = 0.f;
    if (act) {
#pragma unroll
        for (int j = 0; j < 8; j++) pe += __expf(z[j] - pm);
    }
    pe += __shfl_xor(pe, 1);
    pe += __shfl_xor(pe, 2);
    pe += __shfl_xor(pe, 4);
    float lse = __logf(pe);
    if (act) {
        float* po = out + (size_t)r * 40 + cp * 8;
        float4 o0 = make_float4(z[0] - pm - lse, z[1] - pm - lse, z[2] - pm - lse, z[3] - pm - lse);
        float4 o1 = make_float4(z[4] - pm - lse, z[5] - pm - lse, z[6] - pm - lse, z[7] - pm - lse);
        *(float4*)po = o0;
        *(float4*)(po + 4) = o1;
    }
}

// ---------------- launch ----------------

extern "C" void kernel_launch(void* const* d_in, const int* in_sizes, int n_in,
                              void* d_out, int out_size, void* d_ws, size_t ws_size,
                              hipStream_t stream) {
    const float* x     = (const float*)d_in[0];
    const int*   ei    = (const int*)d_in[1];
    const float* W_in  = (const float*)d_in[2];
    const float* b_in  = (const float*)d_in[3];
    const float* W_mid = (const float*)d_in[4];
    const float* b_mid = (const float*)d_in[5];
    const float* W_out = (const float*)d_in[6];
    float* out = (float*)d_out;

    const int* srcv = ei;
    const int* dstv = ei + N_EDGES;

    char* w = (char*)d_ws;
    float* dinv   = (float*)(w);                              // 400 KB
    int2* rowse   = (int2*)(w + (1ull << 19));                // 800 KB
    int* bcnt     = (int*)(w + 1507328);                      // 2 KB
    int* colidx   = (int*)(w + (2ull << 20));                 // 7.2 MB + pad
    unsigned int* ebuf = (unsigned int*)(w + (10ull << 20));  // 7.2 MB
    _Float16* Wt  = (_Float16*)(w + (18ull << 20));           // 155 KB
    _Float16* bufA = (_Float16*)(w + (19ull << 20));          // 8*(N+1)*16 fp16 blocked
    _Float16* bufB = (_Float16*)(w + (45ull << 20));          // 8*(N+1)*16 fp16 blocked
    _Float16* zbuf = (_Float16*)(w + (71ull << 20));          // (N+1)*64 fp16

    _Float16* W1h = Wt;
    _Float16* W1l = Wt + 128 * 128;
    _Float16* W2h = Wt + 2 * 128 * 128;
    _Float16* W2l = Wt + 3 * 128 * 128;
    _Float16* W3h = Wt + 4 * 128 * 128;
    _Float16* W3l = Wt + 4 * 128 * 128 + 48 * 128;

    const int NB_PART = (N_EDGES + 4095) / 4096;  // 391

    // CSR build
    hipMemsetAsync(bcnt, 0, NBUCK * sizeof(int), stream);
    k_zrows<<<1, 256, 0, stream>>>(bufA, zbuf);
    k_bpart<<<NB_PART, 256, 0, stream>>>(srcv, dstv, bcnt, ebuf);
    k_bucket<<<NBUCK, 256, 0, stream>>>(ebuf, bcnt, rowse, dinv, colidx);

    // weight prep (one launch)
    k_wprep_all<<<(304 * 128 + 255) / 256, 256, 0, stream>>>(W_in, W_mid, W_out, Wt);

    const int AGG4_BLOCKS = 8 * ((N_NODES + 127) / 128);  // 8 col-blocks x 782 tiles
    const int AGGO_BLOCKS = N_NODES / 32;                 // 3125

    // Layer 1 (reads fp32 x directly)
    k_gemm128_f32<<<GEMM_GRID, 256, 0, stream>>>(x, W1h, W1l, dinv, bufA);
    k_agg4<<<AGG4_BLOCKS, 256, 0, stream>>>(bufA, rowse, colidx, b_in, bufB);
    // Layer 2
    k_gemm128<<<GEMM_GRID, 256, 0, stream>>>(bufB, W2h, W2l, dinv, bufA);
    k_agg4<<<AGG4_BLOCKS, 256, 0, stream>>>(bufA, rowse, colidx, b_mid, bufB);
    // Layer 3 + fused log_softmax
    k_gemm40<<<G40_GRID, 256, 0, stream>>>(bufB, W3h, W3l, dinv, zbuf);
    k_agg_out<<<AGGO_BLOCKS, 256, 0, stream>>>(zbuf, rowse, colidx, out);
}

// Round 4
// 387.973 us; speedup vs baseline: 1.3026x; 1.3026x over previous
//
#include <hip/hip_runtime.h>
#include <math.h>

#define N_NODES 100000
#define N_EDGES 1600000
#define NBUCK 391          // ceil(100000 / 256)
#define BSTRIDE 4608       // bucket slack stride: mean 4096 + 8 sigma

typedef __attribute__((ext_vector_type(8))) _Float16 h8v;
typedef __attribute__((ext_vector_type(4))) float f32x4;
typedef __attribute__((ext_vector_type(2))) int i32x2;

// ---------------- CSR build + fused prep ----------------
// Blocks 0..390: edge partition into 391 dst-buckets (bpart).
// Blocks 391..542: weight prep (hi/lo split of W1,W2,W3).
// Block 543: zero sentinel rows of gather buffers.

__launch_bounds__(256)
__global__ void k_prep(const int* __restrict__ srcv, const int* __restrict__ dstv,
                       int* __restrict__ bcnt, unsigned int* __restrict__ ebuf,
                       const float* __restrict__ W1, const float* __restrict__ W2,
                       const float* __restrict__ W3, _Float16* __restrict__ Wt,
                       _Float16* __restrict__ bufA, _Float16* __restrict__ zbuf) {
    const int tid = threadIdx.x;
    const int bid = blockIdx.x;

    if (bid >= 391) {
        if (bid == 543) {
            // zero sentinel rows (index N_NODES)
            if (tid < 128) bufA[(size_t)N_NODES * 128 + tid] = (_Float16)0.f;
            if (tid < 64)  zbuf[(size_t)N_NODES * 64 + tid] = (_Float16)0.f;
            return;
        }
        // weight prep: 304*128 elements over blocks 391..542
        int idx = (bid - 391) * 256 + tid;
        if (idx >= 304 * 128) return;
        int n = idx / 128, k = idx % 128;
        const float* W;
        int ncols, nloc;
        _Float16 *ph, *pl;
        if (n < 128)      { W = W1; ncols = 128; nloc = n;       ph = Wt;                 pl = Wt + 128 * 128; }
        else if (n < 256) { W = W2; ncols = 128; nloc = n - 128; ph = Wt + 2 * 128 * 128; pl = Wt + 3 * 128 * 128; }
        else              { W = W3; ncols = 40;  nloc = n - 256; ph = Wt + 4 * 128 * 128; pl = Wt + 4 * 128 * 128 + 48 * 128; }
        float v = (nloc < ncols) ? W[k * ncols + nloc] : 0.f;
        _Float16 hi = (_Float16)v;
        _Float16 lo = (_Float16)(v - (float)hi);
        ph[nloc * 128 + k] = hi;
        pl[nloc * 128 + k] = lo;
        return;
    }

    // ---- bpart ----
    __shared__ int hist[NBUCK];
    __shared__ int cur[NBUCK];
    for (int t = tid; t < NBUCK; t += 256) hist[t] = 0;
    __syncthreads();
    const int base = bid * 4096;
#pragma unroll
    for (int i = 0; i < 16; i++) {
        int e = base + i * 256 + tid;
        if (e < N_EDGES) atomicAdd(&hist[dstv[e] >> 8], 1);
    }
    __syncthreads();
    for (int t = tid; t < NBUCK; t += 256)
        if (hist[t]) cur[t] = t * BSTRIDE + atomicAdd(&bcnt[t], hist[t]);
    __syncthreads();
#pragma unroll
    for (int i = 0; i < 16; i++) {
        int e = base + i * 256 + tid;
        if (e < N_EDGES) {
            int d = dstv[e];
            int p = atomicAdd(&cur[d >> 8], 1);
            ebuf[p] = ((unsigned int)srcv[e] << 8) | (unsigned int)(d & 255);
        }
    }
}

__launch_bounds__(256)
__global__ void k_bucket(const unsigned int* __restrict__ ebuf, const int* __restrict__ bcnt,
                         i32x2* __restrict__ rowse, float* __restrict__ dinv,
                         int* __restrict__ colidx) {
    __shared__ int cnt[256];
    __shared__ int s[256];
    __shared__ int cur[256];
    const int tid = threadIdx.x;
    const int b = blockIdx.x;
    const int e0 = b * BSTRIDE;
    const int e1 = e0 + bcnt[b];
    cnt[tid] = 0;
    __syncthreads();
    for (int e = e0 + tid; e < e1; e += 256) atomicAdd(&cnt[ebuf[e] & 255u], 1);
    __syncthreads();
    int v = cnt[tid];
    int x = v;
    s[tid] = x;
    __syncthreads();
    for (int d = 1; d < 256; d <<= 1) {
        int t = (tid >= d) ? s[tid - d] : 0;
        __syncthreads();
        x += t;
        s[tid] = x;
        __syncthreads();
    }
    int start = e0 + x - v;
    int node = b * 256 + tid;
    if (node < N_NODES) {
        i32x2 se;
        se.x = start;
        se.y = start + v;
        rowse[node] = se;
        dinv[node] = rsqrtf((float)(v + 1));  // +1 self-loop
    }
    cur[tid] = start;
    __syncthreads();
    for (int e = e0 + tid; e < e1; e += 256) {
        unsigned int sd = ebuf[e];
        int pos = atomicAdd(&cur[sd & 255u], 1);
        colidx[pos] = (int)(sd >> 8);
    }
}

// ---------------- Persistent-B MFMA GEMMs ----------------
// B fragments (hi+lo, 64 VGPRs) loaded ONCE per wave; grid-stride loop over
// 32-row tiles. Per tile: 8 independent A-loads + 16 MFMAs (4 acc chains).
// 625 blocks x 5 tiles = 3125 tiles exactly.

#define GEMM_GRID 625
#define NTILES 3125

__launch_bounds__(256, 2)
__global__ void k_gemm128_f32(const float* __restrict__ Af,
                              const _Float16* __restrict__ Wthi, const _Float16* __restrict__ Wtlo,
                              const float* __restrict__ dinv, _Float16* __restrict__ out) {
    const int lane = threadIdx.x & 63;
    const int wi = threadIdx.x >> 6;
    const int nb = wi * 32;
    const int nn = lane & 15;
    const int kq = (lane >> 4) * 8;
    const int quad = lane >> 4;

    h8v bh[4][2], bl[4][2];
#pragma unroll
    for (int c = 0; c < 4; c++)
#pragma unroll
        for (int t = 0; t < 2; t++) {
            int off = (nb + t * 16 + nn) * 128 + c * 32 + kq;
            bh[c][t] = *(const h8v*)(Wthi + off);
            bl[c][t] = *(const h8v*)(Wtlo + off);
        }

    for (int rt = blockIdx.x; rt < NTILES; rt += GEMM_GRID) {
        const int r0 = rt * 32;
        f32x4 acc[2][2] = {};
#pragma unroll
        for (int c = 0; c < 4; c++) {
            h8v a[2];
#pragma unroll
            for (int m = 0; m < 2; m++) {
                const float* p = Af + (size_t)(r0 + m * 16 + nn) * 128 + c * 32 + kq;
                float4 p0 = *(const float4*)p;
                float4 p1 = *(const float4*)(p + 4);
                h8v av = {(_Float16)p0.x, (_Float16)p0.y, (_Float16)p0.z, (_Float16)p0.w,
                          (_Float16)p1.x, (_Float16)p1.y, (_Float16)p1.z, (_Float16)p1.w};
                a[m] = av;
            }
#pragma unroll
            for (int m = 0; m < 2; m++)
#pragma unroll
                for (int t = 0; t < 2; t++) {
                    acc[m][t] = __builtin_amdgcn_mfma_f32_16x16x32_f16(a[m], bh[c][t], acc[m][t], 0, 0, 0);
                    acc[m][t] = __builtin_amdgcn_mfma_f32_16x16x32_f16(a[m], bl[c][t], acc[m][t], 0, 0, 0);
                }
        }
#pragma unroll
        for (int m = 0; m < 2; m++)
#pragma unroll
            for (int reg = 0; reg < 4; reg++) {
                int r = r0 + m * 16 + quad * 4 + reg;
                float dv = dinv[r];
#pragma unroll
                for (int t = 0; t < 2; t++)
                    __builtin_nontemporal_store((_Float16)(acc[m][t][reg] * dv),
                                                out + (size_t)r * 128 + nb + t * 16 + nn);
            }
    }
}

__launch_bounds__(256, 2)
__global__ void k_gemm128(const _Float16* __restrict__ A,
                          const _Float16* __restrict__ Wthi, const _Float16* __restrict__ Wtlo,
                          const float* __restrict__ dinv, _Float16* __restrict__ out) {
    const int lane = threadIdx.x & 63;
    const int wi = threadIdx.x >> 6;
    const int nb = wi * 32;
    const int nn = lane & 15;
    const int kq = (lane >> 4) * 8;
    const int quad = lane >> 4;

    h8v bh[4][2], bl[4][2];
#pragma unroll
    for (int c = 0; c < 4; c++)
#pragma unroll
        for (int t = 0; t < 2; t++) {
            int off = (nb + t * 16 + nn) * 128 + c * 32 + kq;
            bh[c][t] = *(const h8v*)(Wthi + off);
            bl[c][t] = *(const h8v*)(Wtlo + off);
        }

    for (int rt = blockIdx.x; rt < NTILES; rt += GEMM_GRID) {
        const int r0 = rt * 32;
        f32x4 acc[2][2] = {};
#pragma unroll
        for (int c = 0; c < 4; c++) {
            h8v a[2];
#pragma unroll
            for (int m = 0; m < 2; m++)
                a[m] = *(const h8v*)(A + (size_t)(r0 + m * 16 + nn) * 128 + c * 32 + kq);
#pragma unroll
            for (int m = 0; m < 2; m++)
#pragma unroll
                for (int t = 0; t < 2; t++) {
                    acc[m][t] = __builtin_amdgcn_mfma_f32_16x16x32_f16(a[m], bh[c][t], acc[m][t], 0, 0, 0);
                    acc[m][t] = __builtin_amdgcn_mfma_f32_16x16x32_f16(a[m], bl[c][t], acc[m][t], 0, 0, 0);
                }
        }
#pragma unroll
        for (int m = 0; m < 2; m++)
#pragma unroll
            for (int reg = 0; reg < 4; reg++) {
                int r = r0 + m * 16 + quad * 4 + reg;
                float dv = dinv[r];
#pragma unroll
                for (int t = 0; t < 2; t++)
                    __builtin_nontemporal_store((_Float16)(acc[m][t][reg] * dv),
                                                out + (size_t)r * 128 + nb + t * 16 + nn);
            }
    }
}

// Layer-3 GEMM: 40 real cols (48 written) into [N+1][64]-stride buffer.
// Persistent B (24 fragments); wave-level grid-stride over tiles.
#define G40_GRID 160

__launch_bounds__(256, 2)
__global__ void k_gemm40(const _Float16* __restrict__ A,
                         const _Float16* __restrict__ Wthi, const _Float16* __restrict__ Wtlo,
                         const float* __restrict__ dinv, _Float16* __restrict__ out) {
    const int lane = threadIdx.x & 63;
    const int wi = threadIdx.x >> 6;
    const int nn = lane & 15;
    const int kq = (lane >> 4) * 8;
    const int quad = lane >> 4;

    h8v bh[4][3], bl[4][3];
#pragma unroll
    for (int c = 0; c < 4; c++)
#pragma unroll
        for (int t = 0; t < 3; t++) {
            int off = (t * 16 + nn) * 128 + c * 32 + kq;
            bh[c][t] = *(const h8v*)(Wthi + off);
            bl[c][t] = *(const h8v*)(Wtlo + off);
        }

    for (int rt = blockIdx.x * 4 + wi; rt < NTILES; rt += G40_GRID * 4) {
        const int r0 = rt * 32;
        f32x4 acc[2][3] = {};
#pragma unroll
        for (int c = 0; c < 4; c++) {
            h8v a[2];
#pragma unroll
            for (int m = 0; m < 2; m++)
                a[m] = *(const h8v*)(A + (size_t)(r0 + m * 16 + nn) * 128 + c * 32 + kq);
#pragma unroll
            for (int m = 0; m < 2; m++)
#pragma unroll
                for (int t = 0; t < 3; t++) {
                    acc[m][t] = __builtin_amdgcn_mfma_f32_16x16x32_f16(a[m], bh[c][t], acc[m][t], 0, 0, 0);
                    acc[m][t] = __builtin_amdgcn_mfma_f32_16x16x32_f16(a[m], bl[c][t], acc[m][t], 0, 0, 0);
                }
        }
#pragma unroll
        for (int m = 0; m < 2; m++)
#pragma unroll
            for (int reg = 0; reg < 4; reg++) {
                int r = r0 + m * 16 + quad * 4 + reg;
                float dv = dinv[r];
#pragma unroll
                for (int t = 0; t < 3; t++)
                    __builtin_nontemporal_store((_Float16)(acc[m][t][reg] * dv),
                                                out + (size_t)r * 64 + t * 16 + nn);
            }
    }
}

// ---------------- Slot-parallel aggregation (F=128) ----------------
// Round-0 proven form: 4 row slots x 16 lanes, 4-deep gather batch.
// nt hints on streaming accesses (colidx, rowse, output) keep the h gather
// working set resident in L2.

__launch_bounds__(256)
__global__ void k_agg4(const _Float16* __restrict__ hp, const i32x2* __restrict__ rowse,
                       const int* __restrict__ colidx, const float* __restrict__ bias,
                       _Float16* __restrict__ outp) {
    const int lane = threadIdx.x & 63;
    const int wid = (blockIdx.x * blockDim.x + threadIdx.x) >> 6;
    const int rs = lane >> 4;   // row slot 0..3
    const int cp = lane & 15;   // 16B col part
    const int r = wid * 4 + rs;

    const i32x2 se = __builtin_nontemporal_load(rowse + r);
    const int deg = se.y - se.x;
    int m = deg;
    m = max(m, __shfl_xor(m, 16));
    m = max(m, __shfl_xor(m, 32));

    const _Float16* hpc = hp + cp * 8;
    h8v acc = {};
    for (int it = 0; it < m; it += 4) {
        int i0 = se.x + it;
        int s0 = __builtin_nontemporal_load(colidx + i0);
        int s1 = __builtin_nontemporal_load(colidx + i0 + 1);
        int s2 = __builtin_nontemporal_load(colidx + i0 + 2);
        int s3 = __builtin_nontemporal_load(colidx + i0 + 3);
        s0 = (it < deg) ? s0 : N_NODES;
        s1 = (it + 1 < deg) ? s1 : N_NODES;
        s2 = (it + 2 < deg) ? s2 : N_NODES;
        s3 = (it + 3 < deg) ? s3 : N_NODES;
        h8v v0 = *(const h8v*)(hpc + (size_t)s0 * 128);
        h8v v1 = *(const h8v*)(hpc + (size_t)s1 * 128);
        h8v v2 = *(const h8v*)(hpc + (size_t)s2 * 128);
        h8v v3 = *(const h8v*)(hpc + (size_t)s3 * 128);
        acc += v0;
        acc += v1;
        acc += v2;
        acc += v3;
    }

    h8v sv = *(const h8v*)(hpc + (size_t)r * 128);  // self-loop
    float dv = rsqrtf((float)(deg + 1));
    const float* bp = bias + cp * 8;
    float4 b0 = *(const float4*)bp;
    float4 b1 = *(const float4*)(bp + 4);
    float bb[8] = {b0.x, b0.y, b0.z, b0.w, b1.x, b1.y, b1.z, b1.w};
    h8v o;
#pragma unroll
    for (int j = 0; j < 8; j++) {
        float s = (float)acc[j] + (float)sv[j];
        o[j] = (_Float16)fmaxf(fmaf(dv, s, bb[j]), 0.f);
    }
    __builtin_nontemporal_store(o, (h8v*)(outp + (size_t)r * 128 + cp * 8));
}

// ---------------- Final aggregation (64-stride rows) + fused log_softmax ----------------

__launch_bounds__(256)
__global__ void k_agg_out(const _Float16* __restrict__ hp, const i32x2* __restrict__ rowse,
                          const int* __restrict__ colidx, float* __restrict__ out) {
    const int lane = threadIdx.x & 63;
    const int wid = (blockIdx.x * blockDim.x + threadIdx.x) >> 6;
    const int rs = lane >> 3;   // row slot 0..7
    const int cp = lane & 7;    // 16B col part
    const int r = wid * 8 + rs;

    const i32x2 se = __builtin_nontemporal_load(rowse + r);
    const int deg = se.y - se.x;
    int m = deg;
    m = max(m, __shfl_xor(m, 8));
    m = max(m, __shfl_xor(m, 16));
    m = max(m, __shfl_xor(m, 32));

    const _Float16* hpc = hp + cp * 8;
    h8v acc = {};
    for (int it = 0; it < m; it += 4) {
        int i0 = se.x + it;
        int s0 = __builtin_nontemporal_load(colidx + i0);
        int s1 = __builtin_nontemporal_load(colidx + i0 + 1);
        int s2 = __builtin_nontemporal_load(colidx + i0 + 2);
        int s3 = __builtin_nontemporal_load(colidx + i0 + 3);
        s0 = (it < deg) ? s0 : N_NODES;
        s1 = (it + 1 < deg) ? s1 : N_NODES;
        s2 = (it + 2 < deg) ? s2 : N_NODES;
        s3 = (it + 3 < deg) ? s3 : N_NODES;
        h8v v0 = *(const h8v*)(hpc + (size_t)s0 * 64);
        h8v v1 = *(const h8v*)(hpc + (size_t)s1 * 64);
        h8v v2 = *(const h8v*)(hpc + (size_t)s2 * 64);
        h8v v3 = *(const h8v*)(hpc + (size_t)s3 * 64);
        acc += v0;
        acc += v1;
        acc += v2;
        acc += v3;
    }

    h8v sv = *(const h8v*)(hpc + (size_t)r * 64);  // self-loop
    float dv = rsqrtf((float)(deg + 1));
    float z[8];
#pragma unroll
    for (int j = 0; j < 8; j++) z[j] = dv * ((float)acc[j] + (float)sv[j]);

    const bool act = cp < 5;  // cols 0..39
    float pm = -INFINITY;
    if (act) {
#pragma unroll
        for (int j = 0; j < 8; j++) pm = fmaxf(pm, z[j]);
    }
    pm = fmaxf(pm, __shfl_xor(pm, 1));
    pm = fmaxf(pm, __shfl_xor(pm, 2));
    pm = fmaxf(pm, __shfl_xor(pm, 4));
    float pe = 0.f;
    if (act) {
#pragma unroll
        for (int j = 0; j < 8; j++) pe += __expf(z[j] - pm);
    }
    pe += __shfl_xor(pe, 1);
    pe += __shfl_xor(pe, 2);
    pe += __shfl_xor(pe, 4);
    float lse = __logf(pe);
    if (act) {
        float* po = out + (size_t)r * 40 + cp * 8;
        f32x4 o0 = {z[0] - pm - lse, z[1] - pm - lse, z[2] - pm - lse, z[3] - pm - lse};
        f32x4 o1 = {z[4] - pm - lse, z[5] - pm - lse, z[6] - pm - lse, z[7] - pm - lse};
        __builtin_nontemporal_store(o0, (f32x4*)po);
        __builtin_nontemporal_store(o1, (f32x4*)(po + 4));
    }
}

// ---------------- launch ----------------

extern "C" void kernel_launch(void* const* d_in, const int* in_sizes, int n_in,
                              void* d_out, int out_size, void* d_ws, size_t ws_size,
                              hipStream_t stream) {
    const float* x     = (const float*)d_in[0];
    const int*   ei    = (const int*)d_in[1];
    const float* W_in  = (const float*)d_in[2];
    const float* b_in  = (const float*)d_in[3];
    const float* W_mid = (const float*)d_in[4];
    const float* b_mid = (const float*)d_in[5];
    const float* W_out = (const float*)d_in[6];
    float* out = (float*)d_out;

    const int* srcv = ei;
    const int* dstv = ei + N_EDGES;

    char* w = (char*)d_ws;
    float* dinv   = (float*)(w);                              // 400 KB
    i32x2* rowse  = (i32x2*)(w + (1ull << 19));               // 800 KB
    int* bcnt     = (int*)(w + 1507328);                      // 2 KB
    int* colidx   = (int*)(w + (2ull << 20));                 // 7.2 MB + pad
    unsigned int* ebuf = (unsigned int*)(w + (10ull << 20));  // 7.2 MB
    _Float16* Wt  = (_Float16*)(w + (18ull << 20));           // 155 KB
    _Float16* bufA = (_Float16*)(w + (19ull << 20));          // (N+1)*128 fp16
    _Float16* bufB = (_Float16*)(w + (45ull << 20));          // (N+1)*128 fp16
    _Float16* zbuf = (_Float16*)(w + (71ull << 20));          // (N+1)*64 fp16

    _Float16* W1h = Wt;
    _Float16* W1l = Wt + 128 * 128;
    _Float16* W2h = Wt + 2 * 128 * 128;
    _Float16* W2l = Wt + 3 * 128 * 128;
    _Float16* W3h = Wt + 4 * 128 * 128;
    _Float16* W3l = Wt + 4 * 128 * 128 + 48 * 128;

    // CSR build + fused prep (bpart blocks 0..390, wprep 391..542, zrows 543)
    (void)hipMemsetAsync(bcnt, 0, NBUCK * sizeof(int), stream);
    k_prep<<<544, 256, 0, stream>>>(srcv, dstv, bcnt, ebuf, W_in, W_mid, W_out, Wt, bufA, zbuf);
    k_bucket<<<NBUCK, 256, 0, stream>>>(ebuf, bcnt, rowse, dinv, colidx);

    const int AGG4_BLOCKS = N_NODES / 16;   // 6250
    const int AGGO_BLOCKS = N_NODES / 32;   // 3125

    // Layer 1 (reads fp32 x directly)
    k_gemm128_f32<<<GEMM_GRID, 256, 0, stream>>>(x, W1h, W1l, dinv, bufA);
    k_agg4<<<AGG4_BLOCKS, 256, 0, stream>>>(bufA, rowse, colidx, b_in, bufB);
    // Layer 2
    k_gemm128<<<GEMM_GRID, 256, 0, stream>>>(bufB, W2h, W2l, dinv, bufA);
    k_agg4<<<AGG4_BLOCKS, 256, 0, stream>>>(bufA, rowse, colidx, b_mid, bufB);
    // Layer 3 + fused log_softmax
    k_gemm40<<<G40_GRID, 256, 0, stream>>>(bufB, W3h, W3l, dinv, zbuf);
    k_agg_out<<<AGGO_BLOCKS, 256, 0, stream>>>(zbuf, rowse, colidx, out);
}

// Round 5
// 352.967 us; speedup vs baseline: 1.4318x; 1.0992x over previous
//
#include <hip/hip_runtime.h>
#include <math.h>

#define N_NODES 100000
#define N_EDGES 1600000
#define NBUCK 391          // ceil(100000 / 256)
#define BSTRIDE 4608       // bucket slack stride: mean 4096 + 8 sigma

typedef __attribute__((ext_vector_type(8))) _Float16 h8v;
typedef __attribute__((ext_vector_type(4))) float f32x4;
typedef __attribute__((ext_vector_type(2))) int i32x2;

// ---------------- CSR build + fused prep ----------------
// Blocks 0..390: edge partition into 391 dst-buckets (bpart).
// Blocks 391..542: weight prep (hi/lo split of W1,W2,W3).
// Block 543: zero sentinel rows of all gather buffers.

__launch_bounds__(256)
__global__ void k_prep(const int* __restrict__ srcv, const int* __restrict__ dstv,
                       int* __restrict__ bcnt, unsigned int* __restrict__ ebuf,
                       const float* __restrict__ W1, const float* __restrict__ W2,
                       const float* __restrict__ W3, _Float16* __restrict__ Wt,
                       _Float16* __restrict__ bufA, _Float16* __restrict__ bufB,
                       _Float16* __restrict__ zbuf) {
    const int tid = threadIdx.x;
    const int bid = blockIdx.x;

    if (bid >= 391) {
        if (bid == 543) {
            // zero sentinel rows (index N_NODES) of all three gather sources
            if (tid < 128) {
                bufA[(size_t)N_NODES * 128 + tid] = (_Float16)0.f;
                bufB[(size_t)N_NODES * 128 + tid] = (_Float16)0.f;
            }
            if (tid < 64)  zbuf[(size_t)N_NODES * 64 + tid] = (_Float16)0.f;
            return;
        }
        // weight prep: 304*128 elements over blocks 391..542
        int idx = (bid - 391) * 256 + tid;
        if (idx >= 304 * 128) return;
        int n = idx / 128, k = idx % 128;
        const float* W;
        int ncols, nloc;
        _Float16 *ph, *pl;
        if (n < 128)      { W = W1; ncols = 128; nloc = n;       ph = Wt;                 pl = Wt + 128 * 128; }
        else if (n < 256) { W = W2; ncols = 128; nloc = n - 128; ph = Wt + 2 * 128 * 128; pl = Wt + 3 * 128 * 128; }
        else              { W = W3; ncols = 40;  nloc = n - 256; ph = Wt + 4 * 128 * 128; pl = Wt + 4 * 128 * 128 + 48 * 128; }
        float v = (nloc < ncols) ? W[k * ncols + nloc] : 0.f;
        _Float16 hi = (_Float16)v;
        _Float16 lo = (_Float16)(v - (float)hi);
        ph[nloc * 128 + k] = hi;
        pl[nloc * 128 + k] = lo;
        return;
    }

    // ---- bpart ----
    __shared__ int hist[NBUCK];
    __shared__ int cur[NBUCK];
    for (int t = tid; t < NBUCK; t += 256) hist[t] = 0;
    __syncthreads();
    const int base = bid * 4096;
#pragma unroll
    for (int i = 0; i < 16; i++) {
        int e = base + i * 256 + tid;
        if (e < N_EDGES) atomicAdd(&hist[dstv[e] >> 8], 1);
    }
    __syncthreads();
    for (int t = tid; t < NBUCK; t += 256)
        if (hist[t]) cur[t] = t * BSTRIDE + atomicAdd(&bcnt[t], hist[t]);
    __syncthreads();
#pragma unroll
    for (int i = 0; i < 16; i++) {
        int e = base + i * 256 + tid;
        if (e < N_EDGES) {
            int d = dstv[e];
            int p = atomicAdd(&cur[d >> 8], 1);
            ebuf[p] = ((unsigned int)srcv[e] << 8) | (unsigned int)(d & 255);
        }
    }
}

__launch_bounds__(256)
__global__ void k_bucket(const unsigned int* __restrict__ ebuf, const int* __restrict__ bcnt,
                         i32x2* __restrict__ rowse, float* __restrict__ dinv,
                         int* __restrict__ colidx) {
    __shared__ int cnt[256];
    __shared__ int s[256];
    __shared__ int cur[256];
    const int tid = threadIdx.x;
    const int b = blockIdx.x;
    const int e0 = b * BSTRIDE;
    const int e1 = e0 + bcnt[b];
    cnt[tid] = 0;
    __syncthreads();
    for (int e = e0 + tid; e < e1; e += 256) atomicAdd(&cnt[ebuf[e] & 255u], 1);
    __syncthreads();
    int v = cnt[tid];
    int x = v;
    s[tid] = x;
    __syncthreads();
    for (int d = 1; d < 256; d <<= 1) {
        int t = (tid >= d) ? s[tid - d] : 0;
        __syncthreads();
        x += t;
        s[tid] = x;
        __syncthreads();
    }
    int start = e0 + x - v;
    int node = b * 256 + tid;
    if (node < N_NODES) {
        i32x2 se;
        se.x = start;
        se.y = start + v;
        rowse[node] = se;
        dinv[node] = rsqrtf((float)(v + 1));  // +1 self-loop
    }
    cur[tid] = start;
    __syncthreads();
    for (int e = e0 + tid; e < e1; e += 256) {
        unsigned int sd = ebuf[e];
        int pos = atomicAdd(&cur[sd & 255u], 1);
        colidx[pos] = (int)(sd >> 8);
    }
}

// ---------------- Layer-1 GEMM (fp32 x input) ----------------
// Persistent-B; grid-stride over 32-row tiles. 625 blocks x 5 tiles.

#define GEMM_GRID 625
#define NTILES 3125

__launch_bounds__(256, 2)
__global__ void k_gemm128_f32(const float* __restrict__ Af,
                              const _Float16* __restrict__ Wthi, const _Float16* __restrict__ Wtlo,
                              const float* __restrict__ dinv, _Float16* __restrict__ out) {
    const int lane = threadIdx.x & 63;
    const int wi = threadIdx.x >> 6;
    const int nb = wi * 32;
    const int nn = lane & 15;
    const int kq = (lane >> 4) * 8;
    const int quad = lane >> 4;

    h8v bh[4][2], bl[4][2];
#pragma unroll
    for (int c = 0; c < 4; c++)
#pragma unroll
        for (int t = 0; t < 2; t++) {
            int off = (nb + t * 16 + nn) * 128 + c * 32 + kq;
            bh[c][t] = *(const h8v*)(Wthi + off);
            bl[c][t] = *(const h8v*)(Wtlo + off);
        }

    for (int rt = blockIdx.x; rt < NTILES; rt += GEMM_GRID) {
        const int r0 = rt * 32;
        f32x4 acc[2][2] = {};
#pragma unroll
        for (int c = 0; c < 4; c++) {
            h8v a[2];
#pragma unroll
            for (int m = 0; m < 2; m++) {
                const float* p = Af + (size_t)(r0 + m * 16 + nn) * 128 + c * 32 + kq;
                float4 p0 = *(const float4*)p;
                float4 p1 = *(const float4*)(p + 4);
                h8v av = {(_Float16)p0.x, (_Float16)p0.y, (_Float16)p0.z, (_Float16)p0.w,
                          (_Float16)p1.x, (_Float16)p1.y, (_Float16)p1.z, (_Float16)p1.w};
                a[m] = av;
            }
#pragma unroll
            for (int m = 0; m < 2; m++)
#pragma unroll
                for (int t = 0; t < 2; t++) {
                    acc[m][t] = __builtin_amdgcn_mfma_f32_16x16x32_f16(a[m], bh[c][t], acc[m][t], 0, 0, 0);
                    acc[m][t] = __builtin_amdgcn_mfma_f32_16x16x32_f16(a[m], bl[c][t], acc[m][t], 0, 0, 0);
                }
        }
#pragma unroll
        for (int m = 0; m < 2; m++)
#pragma unroll
            for (int reg = 0; reg < 4; reg++) {
                int r = r0 + m * 16 + quad * 4 + reg;
                float dv = dinv[r];
#pragma unroll
                for (int t = 0; t < 2; t++)
                    out[(size_t)r * 128 + nb + t * 16 + nn] = (_Float16)(acc[m][t][reg] * dv);
            }
    }
}

// ---------------- Fused aggregation + GEMM (agg -> relu/bias -> @W -> out) ----------------
// Phase A: proven agg4 gather shape (4 row slots x 16 lanes, 256B rows, 4-deep
// batches); result rows staged in LDS as XOR-swizzled 16B chunks.
// Phase B: persistent-B MFMA GEMM on the 32-row tile from LDS.
// One 32-row tile per block (3125 blocks) to keep gather concurrency high;
// B-fragment reloads are L2-hits (W is 128KB hot).

__launch_bounds__(256, 2)
__global__ void k_fused128(const _Float16* __restrict__ hp, const i32x2* __restrict__ rowse,
                           const int* __restrict__ colidx, const float* __restrict__ bias,
                           const float* __restrict__ dinv,
                           const _Float16* __restrict__ Wthi, const _Float16* __restrict__ Wtlo,
                           _Float16* __restrict__ out) {
    __shared__ __align__(16) _Float16 As[32 * 128];
    const int lane = threadIdx.x & 63;
    const int wi = threadIdx.x >> 6;
    const int nn = lane & 15;
    const int quad = lane >> 4;
    const int kq = quad * 8;
    const int nb = wi * 32;

    h8v bh[4][2], bl[4][2];
#pragma unroll
    for (int c = 0; c < 4; c++)
#pragma unroll
        for (int t = 0; t < 2; t++) {
            int off = (nb + t * 16 + nn) * 128 + c * 32 + kq;
            bh[c][t] = *(const h8v*)(Wthi + off);
            bl[c][t] = *(const h8v*)(Wtlo + off);
        }

    const int r0 = blockIdx.x * 32;

    // ---- phase A: aggregate 32 rows (wave wi owns local rows wi*8 .. wi*8+7) ----
    const int rs = quad;    // row slot 0..3
    const int cp = nn;      // 16B col part 0..15
    const _Float16* hpc = hp + cp * 8;
    const float* bp = bias + cp * 8;
    float4 b0 = *(const float4*)bp;
    float4 b1 = *(const float4*)(bp + 4);
    float bb[8] = {b0.x, b0.y, b0.z, b0.w, b1.x, b1.y, b1.z, b1.w};
#pragma unroll
    for (int p = 0; p < 2; p++) {
        const int rl = wi * 8 + p * 4 + rs;
        const int r = r0 + rl;
        const i32x2 se = rowse[r];
        const int deg = se.y - se.x;
        int m = deg;
        m = max(m, __shfl_xor(m, 16));
        m = max(m, __shfl_xor(m, 32));
        h8v acc = {};
        for (int it = 0; it < m; it += 4) {
            int i0 = se.x + it;
            int s0 = colidx[i0];
            int s1 = colidx[i0 + 1];
            int s2 = colidx[i0 + 2];
            int s3 = colidx[i0 + 3];
            s0 = (it < deg) ? s0 : N_NODES;
            s1 = (it + 1 < deg) ? s1 : N_NODES;
            s2 = (it + 2 < deg) ? s2 : N_NODES;
            s3 = (it + 3 < deg) ? s3 : N_NODES;
            h8v v0 = *(const h8v*)(hpc + (size_t)s0 * 128);
            h8v v1 = *(const h8v*)(hpc + (size_t)s1 * 128);
            h8v v2 = *(const h8v*)(hpc + (size_t)s2 * 128);
            h8v v3 = *(const h8v*)(hpc + (size_t)s3 * 128);
            acc += v0;
            acc += v1;
            acc += v2;
            acc += v3;
        }
        h8v sv = *(const h8v*)(hpc + (size_t)r * 128);  // self-loop
        float dv = rsqrtf((float)(deg + 1));
        h8v o;
#pragma unroll
        for (int j = 0; j < 8; j++) {
            float sx = (float)acc[j] + (float)sv[j];
            o[j] = (_Float16)fmaxf(fmaf(dv, sx, bb[j]), 0.f);
        }
        *(h8v*)(As + rl * 128 + ((cp ^ (rl & 15)) * 8)) = o;
    }
    __syncthreads();

    // ---- phase B: 32x128 tile @ W (this wave's 32 cols) ----
    f32x4 acc2[2][2] = {};
#pragma unroll
    for (int c = 0; c < 4; c++) {
        h8v a[2];
#pragma unroll
        for (int mm = 0; mm < 2; mm++) {
            int R = mm * 16 + nn;
            int ch = (c * 4 + quad) ^ (R & 15);
            a[mm] = *(const h8v*)(As + R * 128 + ch * 8);
        }
#pragma unroll
        for (int mm = 0; mm < 2; mm++)
#pragma unroll
            for (int t = 0; t < 2; t++) {
                acc2[mm][t] = __builtin_amdgcn_mfma_f32_16x16x32_f16(a[mm], bh[c][t], acc2[mm][t], 0, 0, 0);
                acc2[mm][t] = __builtin_amdgcn_mfma_f32_16x16x32_f16(a[mm], bl[c][t], acc2[mm][t], 0, 0, 0);
            }
    }
#pragma unroll
    for (int mm = 0; mm < 2; mm++)
#pragma unroll
        for (int reg = 0; reg < 4; reg++) {
            int r = r0 + mm * 16 + quad * 4 + reg;
            float dv = dinv[r];
#pragma unroll
            for (int t = 0; t < 2; t++)
                out[(size_t)r * 128 + nb + t * 16 + nn] = (_Float16)(acc2[mm][t][reg] * dv);
        }
}

// Fused aggregation + layer-3 GEMM (48 cols) into [N+1][64]-stride buffer.
// Phase B uses waves 0..2 (t = wi), wave 3 idles there.
__launch_bounds__(256, 2)
__global__ void k_fused40(const _Float16* __restrict__ hp, const i32x2* __restrict__ rowse,
                          const int* __restrict__ colidx, const float* __restrict__ bias,
                          const float* __restrict__ dinv,
                          const _Float16* __restrict__ Wthi, const _Float16* __restrict__ Wtlo,
                          _Float16* __restrict__ out) {
    __shared__ __align__(16) _Float16 As[32 * 128];
    const int lane = threadIdx.x & 63;
    const int wi = threadIdx.x >> 6;
    const int nn = lane & 15;
    const int quad = lane >> 4;
    const int kq = quad * 8;

    h8v bh[4], bl[4];
    if (wi < 3) {
#pragma unroll
        for (int c = 0; c < 4; c++) {
            int off = (wi * 16 + nn) * 128 + c * 32 + kq;
            bh[c] = *(const h8v*)(Wthi + off);
            bl[c] = *(const h8v*)(Wtlo + off);
        }
    }

    const int r0 = blockIdx.x * 32;

    // ---- phase A ----
    const int rs = quad;
    const int cp = nn;
    const _Float16* hpc = hp + cp * 8;
    const float* bp = bias + cp * 8;
    float4 b0 = *(const float4*)bp;
    float4 b1 = *(const float4*)(bp + 4);
    float bb[8] = {b0.x, b0.y, b0.z, b0.w, b1.x, b1.y, b1.z, b1.w};
#pragma unroll
    for (int p = 0; p < 2; p++) {
        const int rl = wi * 8 + p * 4 + rs;
        const int r = r0 + rl;
        const i32x2 se = rowse[r];
        const int deg = se.y - se.x;
        int m = deg;
        m = max(m, __shfl_xor(m, 16));
        m = max(m, __shfl_xor(m, 32));
        h8v acc = {};
        for (int it = 0; it < m; it += 4) {
            int i0 = se.x + it;
            int s0 = colidx[i0];
            int s1 = colidx[i0 + 1];
            int s2 = colidx[i0 + 2];
            int s3 = colidx[i0 + 3];
            s0 = (it < deg) ? s0 : N_NODES;
            s1 = (it + 1 < deg) ? s1 : N_NODES;
            s2 = (it + 2 < deg) ? s2 : N_NODES;
            s3 = (it + 3 < deg) ? s3 : N_NODES;
            h8v v0 = *(const h8v*)(hpc + (size_t)s0 * 128);
            h8v v1 = *(const h8v*)(hpc + (size_t)s1 * 128);
            h8v v2 = *(const h8v*)(hpc + (size_t)s2 * 128);
            h8v v3 = *(const h8v*)(hpc + (size_t)s3 * 128);
            acc += v0;
            acc += v1;
            acc += v2;
            acc += v3;
        }
        h8v sv = *(const h8v*)(hpc + (size_t)r * 128);  // self-loop
        float dv = rsqrtf((float)(deg + 1));
        h8v o;
#pragma unroll
        for (int j = 0; j < 8; j++) {
            float sx = (float)acc[j] + (float)sv[j];
            o[j] = (_Float16)fmaxf(fmaf(dv, sx, bb[j]), 0.f);
        }
        *(h8v*)(As + rl * 128 + ((cp ^ (rl & 15)) * 8)) = o;
    }
    __syncthreads();

    // ---- phase B: 32x128 tile @ W3 (wave wi -> cols wi*16..wi*16+15) ----
    if (wi < 3) {
        f32x4 acc2[2] = {};
#pragma unroll
        for (int c = 0; c < 4; c++) {
            h8v a[2];
#pragma unroll
            for (int mm = 0; mm < 2; mm++) {
                int R = mm * 16 + nn;
                int ch = (c * 4 + quad) ^ (R & 15);
                a[mm] = *(const h8v*)(As + R * 128 + ch * 8);
            }
#pragma unroll
            for (int mm = 0; mm < 2; mm++) {
                acc2[mm] = __builtin_amdgcn_mfma_f32_16x16x32_f16(a[mm], bh[c], acc2[mm], 0, 0, 0);
                acc2[mm] = __builtin_amdgcn_mfma_f32_16x16x32_f16(a[mm], bl[c], acc2[mm], 0, 0, 0);
            }
        }
#pragma unroll
        for (int mm = 0; mm < 2; mm++)
#pragma unroll
            for (int reg = 0; reg < 4; reg++) {
                int r = r0 + mm * 16 + quad * 4 + reg;
                float dv = dinv[r];
                out[(size_t)r * 64 + wi * 16 + nn] = (_Float16)(acc2[mm][reg] * dv);
            }
    }
}

// ---------------- Final aggregation (64-stride rows) + fused log_softmax ----------------

__launch_bounds__(256)
__global__ void k_agg_out(const _Float16* __restrict__ hp, const i32x2* __restrict__ rowse,
                          const int* __restrict__ colidx, float* __restrict__ out) {
    const int lane = threadIdx.x & 63;
    const int wid = (blockIdx.x * blockDim.x + threadIdx.x) >> 6;
    const int rs = lane >> 3;   // row slot 0..7
    const int cp = lane & 7;    // 16B col part
    const int r = wid * 8 + rs;

    const i32x2 se = rowse[r];
    const int deg = se.y - se.x;
    int m = deg;
    m = max(m, __shfl_xor(m, 8));
    m = max(m, __shfl_xor(m, 16));
    m = max(m, __shfl_xor(m, 32));

    const _Float16* hpc = hp + cp * 8;
    h8v acc = {};
    for (int it = 0; it < m; it += 4) {
        int i0 = se.x + it;
        int s0 = colidx[i0];
        int s1 = colidx[i0 + 1];
        int s2 = colidx[i0 + 2];
        int s3 = colidx[i0 + 3];
        s0 = (it < deg) ? s0 : N_NODES;
        s1 = (it + 1 < deg) ? s1 : N_NODES;
        s2 = (it + 2 < deg) ? s2 : N_NODES;
        s3 = (it + 3 < deg) ? s3 : N_NODES;
        h8v v0 = *(const h8v*)(hpc + (size_t)s0 * 64);
        h8v v1 = *(const h8v*)(hpc + (size_t)s1 * 64);
        h8v v2 = *(const h8v*)(hpc + (size_t)s2 * 64);
        h8v v3 = *(const h8v*)(hpc + (size_t)s3 * 64);
        acc += v0;
        acc += v1;
        acc += v2;
        acc += v3;
    }

    h8v sv = *(const h8v*)(hpc + (size_t)r * 64);  // self-loop
    float dv = rsqrtf((float)(deg + 1));
    float z[8];
#pragma unroll
    for (int j = 0; j < 8; j++) z[j] = dv * ((float)acc[j] + (float)sv[j]);

    const bool act = cp < 5;  // cols 0..39
    float pm = -INFINITY;
    if (act) {
#pragma unroll
        for (int j = 0; j < 8; j++) pm = fmaxf(pm, z[j]);
    }
    pm = fmaxf(pm, __shfl_xor(pm, 1));
    pm = fmaxf(pm, __shfl_xor(pm, 2));
    pm = fmaxf(pm, __shfl_xor(pm, 4));
    float pe = 0.f;
    if (act) {
#pragma unroll
        for (int j = 0; j < 8; j++) pe += __expf(z[j] - pm);
    }
    pe += __shfl_xor(pe, 1);
    pe += __shfl_xor(pe, 2);
    pe += __shfl_xor(pe, 4);
    float lse = __logf(pe);
    if (act) {
        float* po = out + (size_t)r * 40 + cp * 8;
        float4 o0 = make_float4(z[0] - pm - lse, z[1] - pm - lse, z[2] - pm - lse, z[3] - pm - lse);
        float4 o1 = make_float4(z[4] - pm - lse, z[5] - pm - lse, z[6] - pm - lse, z[7] - pm - lse);
        *(float4*)po = o0;
        *(float4*)(po + 4) = o1;
    }
}

// ---------------- launch ----------------

extern "C" void kernel_launch(void* const* d_in, const int* in_sizes, int n_in,
                              void* d_out, int out_size, void* d_ws, size_t ws_size,
                              hipStream_t stream) {
    const float* x     = (const float*)d_in[0];
    const int*   ei    = (const int*)d_in[1];
    const float* W_in  = (const float*)d_in[2];
    const float* b_in  = (const float*)d_in[3];
    const float* W_mid = (const float*)d_in[4];
    const float* b_mid = (const float*)d_in[5];
    const float* W_out = (const float*)d_in[6];
    float* out = (float*)d_out;

    const int* srcv = ei;
    const int* dstv = ei + N_EDGES;

    char* w = (char*)d_ws;
    float* dinv   = (float*)(w);                              // 400 KB
    i32x2* rowse  = (i32x2*)(w + (1ull << 19));               // 800 KB
    int* bcnt     = (int*)(w + 1507328);                      // 2 KB
    int* colidx   = (int*)(w + (2ull << 20));                 // 7.2 MB + pad
    unsigned int* ebuf = (unsigned int*)(w + (10ull << 20));  // 7.2 MB
    _Float16* Wt  = (_Float16*)(w + (18ull << 20));           // 155 KB
    _Float16* bufA = (_Float16*)(w + (19ull << 20));          // (N+1)*128 fp16
    _Float16* bufB = (_Float16*)(w + (45ull << 20));          // (N+1)*128 fp16
    _Float16* zbuf = (_Float16*)(w + (71ull << 20));          // (N+1)*64 fp16

    _Float16* W1h = Wt;
    _Float16* W1l = Wt + 128 * 128;
    _Float16* W2h = Wt + 2 * 128 * 128;
    _Float16* W2l = Wt + 3 * 128 * 128;
    _Float16* W3h = Wt + 4 * 128 * 128;
    _Float16* W3l = Wt + 4 * 128 * 128 + 48 * 128;

    // CSR build + fused prep (bpart blocks 0..390, wprep 391..542, zrows 543)
    (void)hipMemsetAsync(bcnt, 0, NBUCK * sizeof(int), stream);
    k_prep<<<544, 256, 0, stream>>>(srcv, dstv, bcnt, ebuf, W_in, W_mid, W_out, Wt, bufA, bufB, zbuf);
    k_bucket<<<NBUCK, 256, 0, stream>>>(ebuf, bcnt, rowse, dinv, colidx);

    // Layer 1 GEMM (reads fp32 x directly) -> bufA (pre-scaled by dinv)
    k_gemm128_f32<<<GEMM_GRID, 256, 0, stream>>>(x, W1h, W1l, dinv, bufA);
    // Layer 1 agg + Layer 2 GEMM fused: gather bufA -> @W2 -> bufB
    k_fused128<<<NTILES, 256, 0, stream>>>(bufA, rowse, colidx, b_in, dinv, W2h, W2l, bufB);
    // Layer 2 agg + Layer 3 GEMM fused: gather bufB -> @W3 -> zbuf
    k_fused40<<<NTILES, 256, 0, stream>>>(bufB, rowse, colidx, b_mid, dinv, W3h, W3l, zbuf);
    // Final aggregation + log_softmax
    k_agg_out<<<N_NODES / 32, 256, 0, stream>>>(zbuf, rowse, colidx, out);
}

// Round 6
// 347.942 us; speedup vs baseline: 1.4525x; 1.0144x over previous
//
#include <hip/hip_runtime.h>
#include <math.h>

#define N_NODES 100000
#define N_EDGES 1600000
#define NBUCK 391          // ceil(100000 / 256)
#define BSTRIDE 4608       // bucket slack stride: mean 4096 + 8 sigma

typedef __attribute__((ext_vector_type(8))) _Float16 h8v;
typedef __attribute__((ext_vector_type(4))) float f32x4;
typedef __attribute__((ext_vector_type(2))) int i32x2;

#define GEMM_GRID 625
#define NTILES 3125

// ---------------- mega-prep: L1 GEMM + bpart + wprep + zrows ----------------
// Convention change: h buffers hold UNSCALED x@W rows; gathers apply dinv[src].
// This makes layer-1 GEMM independent of the CSR build, so it co-runs here.
// Blocks 0..624: layer-1 GEMM (inline W1 hi/lo split, grid-stride 5 tiles).
// Blocks 625..1015: edge partition into 391 dst-buckets.
// Blocks 1016..1103: weight prep for W2, W3 (hi/lo split).
// Block 1104: zero sentinel rows of bufA/bufB/zbuf.

__global__ void k_prep(const int* __restrict__ srcv, const int* __restrict__ dstv,
                       int* __restrict__ bcnt, unsigned int* __restrict__ ebuf,
                       const float* __restrict__ x, const float* __restrict__ W1,
                       const float* __restrict__ W2, const float* __restrict__ W3,
                       _Float16* __restrict__ Wt,
                       _Float16* __restrict__ bufA, _Float16* __restrict__ bufB,
                       _Float16* __restrict__ zbuf) {
    const int tid = threadIdx.x;
    const int bid = blockIdx.x;

    if (bid < 625) {
        // ---- layer-1 GEMM: bufA = x @ W1 (fp16, unscaled) ----
        const int lane = tid & 63;
        const int wi = tid >> 6;
        const int nb = wi * 32;
        const int nn = lane & 15;
        const int quad = lane >> 4;
        const int kq = quad * 8;

        h8v bh[4][2], bl[4][2];
#pragma unroll
        for (int c = 0; c < 4; c++)
#pragma unroll
            for (int t = 0; t < 2; t++) {
#pragma unroll
                for (int j = 0; j < 8; j++) {
                    float w = W1[(c * 32 + kq + j) * 128 + nb + t * 16 + nn];
                    _Float16 hi = (_Float16)w;
                    bh[c][t][j] = hi;
                    bl[c][t][j] = (_Float16)(w - (float)hi);
                }
            }

        for (int rt = bid; rt < NTILES; rt += GEMM_GRID) {
            const int r0 = rt * 32;
            f32x4 acc[2][2] = {};
#pragma unroll
            for (int c = 0; c < 4; c++) {
                h8v a[2];
#pragma unroll
                for (int m = 0; m < 2; m++) {
                    const float* p = x + (size_t)(r0 + m * 16 + nn) * 128 + c * 32 + kq;
                    float4 p0 = *(const float4*)p;
                    float4 p1 = *(const float4*)(p + 4);
                    h8v av = {(_Float16)p0.x, (_Float16)p0.y, (_Float16)p0.z, (_Float16)p0.w,
                              (_Float16)p1.x, (_Float16)p1.y, (_Float16)p1.z, (_Float16)p1.w};
                    a[m] = av;
                }
#pragma unroll
                for (int m = 0; m < 2; m++)
#pragma unroll
                    for (int t = 0; t < 2; t++) {
                        acc[m][t] = __builtin_amdgcn_mfma_f32_16x16x32_f16(a[m], bh[c][t], acc[m][t], 0, 0, 0);
                        acc[m][t] = __builtin_amdgcn_mfma_f32_16x16x32_f16(a[m], bl[c][t], acc[m][t], 0, 0, 0);
                    }
            }
#pragma unroll
            for (int m = 0; m < 2; m++)
#pragma unroll
                for (int reg = 0; reg < 4; reg++) {
                    int r = r0 + m * 16 + quad * 4 + reg;
#pragma unroll
                    for (int t = 0; t < 2; t++)
                        bufA[(size_t)r * 128 + nb + t * 16 + nn] = (_Float16)acc[m][t][reg];
                }
        }
        return;
    }

    if (bid >= 1016) {
        if (bid == 1104) {
            if (tid < 128) {
                bufA[(size_t)N_NODES * 128 + tid] = (_Float16)0.f;
                bufB[(size_t)N_NODES * 128 + tid] = (_Float16)0.f;
            }
            if (tid < 64)  zbuf[(size_t)N_NODES * 64 + tid] = (_Float16)0.f;
            return;
        }
        // weight prep for W2 (128 cols) + W3 (48 cols, zero-padded): 176*128 elems
        int idx = (bid - 1016) * 256 + tid;
        if (idx >= 176 * 128) return;
        int n = idx / 128, k = idx % 128;
        _Float16 *ph, *pl;
        float v;
        if (n < 128) {
            v = W2[k * 128 + n];
            ph = Wt + 2 * 128 * 128; pl = Wt + 3 * 128 * 128;
        } else {
            int nloc = n - 128;
            v = (nloc < 40) ? W3[k * 40 + nloc] : 0.f;
            ph = Wt + 4 * 128 * 128; pl = Wt + 4 * 128 * 128 + 48 * 128;
            n = nloc;
        }
        _Float16 hi = (_Float16)v;
        _Float16 lo = (_Float16)(v - (float)hi);
        ph[n * 128 + k] = hi;
        pl[n * 128 + k] = lo;
        return;
    }

    // ---- bpart (blocks 625..1015) ----
    __shared__ int hist[NBUCK];
    __shared__ int cur[NBUCK];
    for (int t = tid; t < NBUCK; t += 256) hist[t] = 0;
    __syncthreads();
    const int base = (bid - 625) * 4096;
#pragma unroll
    for (int i = 0; i < 16; i++) {
        int e = base + i * 256 + tid;
        if (e < N_EDGES) atomicAdd(&hist[dstv[e] >> 8], 1);
    }
    __syncthreads();
    for (int t = tid; t < NBUCK; t += 256)
        if (hist[t]) cur[t] = t * BSTRIDE + atomicAdd(&bcnt[t], hist[t]);
    __syncthreads();
#pragma unroll
    for (int i = 0; i < 16; i++) {
        int e = base + i * 256 + tid;
        if (e < N_EDGES) {
            int d = dstv[e];
            int p = atomicAdd(&cur[d >> 8], 1);
            ebuf[p] = ((unsigned int)srcv[e] << 8) | (unsigned int)(d & 255);
        }
    }
}

__launch_bounds__(256)
__global__ void k_bucket(const unsigned int* __restrict__ ebuf, const int* __restrict__ bcnt,
                         i32x2* __restrict__ rowse, float* __restrict__ dinv,
                         int* __restrict__ colidx) {
    __shared__ int cnt[256];
    __shared__ int s[256];
    __shared__ int cur[256];
    const int tid = threadIdx.x;
    const int b = blockIdx.x;
    if (b == 0 && tid == 0) dinv[N_NODES] = 0.f;  // sentinel (must be finite)
    const int e0 = b * BSTRIDE;
    const int e1 = e0 + bcnt[b];
    cnt[tid] = 0;
    __syncthreads();
    for (int e = e0 + tid; e < e1; e += 256) atomicAdd(&cnt[ebuf[e] & 255u], 1);
    __syncthreads();
    int v = cnt[tid];
    int x = v;
    s[tid] = x;
    __syncthreads();
    for (int d = 1; d < 256; d <<= 1) {
        int t = (tid >= d) ? s[tid - d] : 0;
        __syncthreads();
        x += t;
        s[tid] = x;
        __syncthreads();
    }
    int start = e0 + x - v;
    int node = b * 256 + tid;
    if (node < N_NODES) {
        i32x2 se;
        se.x = start;
        se.y = start + v;
        rowse[node] = se;
        dinv[node] = rsqrtf((float)(v + 1));  // +1 self-loop
    }
    cur[tid] = start;
    __syncthreads();
    for (int e = e0 + tid; e < e1; e += 256) {
        unsigned int sd = ebuf[e];
        int pos = atomicAdd(&cur[sd & 255u], 1);
        colidx[pos] = (int)(sd >> 8);
    }
}

// ---------------- Fused aggregation + GEMM, 16-row tiles ----------------
// Phase A: EXACT agg4 shape — 6250 blocks, each wave gathers 4 rows (quad =
// row slot, nn = 16B chunk) in one pass; dinv[src] applied per term; fp32
// accumulate. Result relu(bias(...)) rows staged in LDS (XOR-swizzled).
// Phase B: 16x128 @ W tile; B fragments loaded from L2 after the barrier
// (keeps gather-phase VGPR low -> full occupancy).

__launch_bounds__(256)
__global__ void k_fused128(const _Float16* __restrict__ hp, const i32x2* __restrict__ rowse,
                           const int* __restrict__ colidx, const float* __restrict__ bias,
                           const float* __restrict__ dinv,
                           const _Float16* __restrict__ Wthi, const _Float16* __restrict__ Wtlo,
                           _Float16* __restrict__ out) {
    __shared__ __align__(16) _Float16 As[16 * 128];
    const int lane = threadIdx.x & 63;
    const int wi = threadIdx.x >> 6;
    const int nn = lane & 15;
    const int quad = lane >> 4;
    const int r0 = blockIdx.x * 16;

    // ---- phase A ----
    {
        const int rl = wi * 4 + quad;
        const int r = r0 + rl;
        const i32x2 se = rowse[r];
        const int deg = se.y - se.x;
        int m = deg;
        m = max(m, __shfl_xor(m, 16));
        m = max(m, __shfl_xor(m, 32));
        const _Float16* hpc = hp + nn * 8;
        float accf[8] = {};
        for (int it = 0; it < m; it += 4) {
            int i0 = se.x + it;
            int s0 = colidx[i0];
            int s1 = colidx[i0 + 1];
            int s2 = colidx[i0 + 2];
            int s3 = colidx[i0 + 3];
            s0 = (it < deg) ? s0 : N_NODES;
            s1 = (it + 1 < deg) ? s1 : N_NODES;
            s2 = (it + 2 < deg) ? s2 : N_NODES;
            s3 = (it + 3 < deg) ? s3 : N_NODES;
            float d0 = dinv[s0];
            float d1 = dinv[s1];
            float d2 = dinv[s2];
            float d3 = dinv[s3];
            h8v v0 = *(const h8v*)(hpc + (size_t)s0 * 128);
            h8v v1 = *(const h8v*)(hpc + (size_t)s1 * 128);
            h8v v2 = *(const h8v*)(hpc + (size_t)s2 * 128);
            h8v v3 = *(const h8v*)(hpc + (size_t)s3 * 128);
#pragma unroll
            for (int j = 0; j < 8; j++) {
                accf[j] = fmaf(d0, (float)v0[j], accf[j]);
                accf[j] = fmaf(d1, (float)v1[j], accf[j]);
                accf[j] = fmaf(d2, (float)v2[j], accf[j]);
                accf[j] = fmaf(d3, (float)v3[j], accf[j]);
            }
        }
        h8v sv = *(const h8v*)(hpc + (size_t)r * 128);  // self-loop (unscaled)
        float dv = rsqrtf((float)(deg + 1));
        const float* bp = bias + nn * 8;
        float4 b0 = *(const float4*)bp;
        float4 b1 = *(const float4*)(bp + 4);
        float bb[8] = {b0.x, b0.y, b0.z, b0.w, b1.x, b1.y, b1.z, b1.w};
        h8v o;
#pragma unroll
        for (int j = 0; j < 8; j++) {
            float sx = accf[j] + dv * (float)sv[j];
            o[j] = (_Float16)fmaxf(fmaf(dv, sx, bb[j]), 0.f);
        }
        *(h8v*)(As + rl * 128 + ((nn ^ rl) * 8)) = o;
    }
    __syncthreads();

    // ---- phase B: 16x128 tile @ W (wave wi -> cols wi*32..+31) ----
    const int nb = wi * 32;
    const int kq = quad * 8;
    f32x4 acc2[2] = {};
#pragma unroll
    for (int c = 0; c < 4; c++) {
        int ch = (c * 4 + quad) ^ nn;
        h8v a = *(const h8v*)(As + nn * 128 + ch * 8);
#pragma unroll
        for (int t = 0; t < 2; t++) {
            int off = (nb + t * 16 + nn) * 128 + c * 32 + kq;
            h8v bhv = *(const h8v*)(Wthi + off);
            h8v blv = *(const h8v*)(Wtlo + off);
            acc2[t] = __builtin_amdgcn_mfma_f32_16x16x32_f16(a, bhv, acc2[t], 0, 0, 0);
            acc2[t] = __builtin_amdgcn_mfma_f32_16x16x32_f16(a, blv, acc2[t], 0, 0, 0);
        }
    }
#pragma unroll
    for (int reg = 0; reg < 4; reg++) {
        int r = r0 + quad * 4 + reg;
#pragma unroll
        for (int t = 0; t < 2; t++)
            out[(size_t)r * 128 + nb + t * 16 + nn] = (_Float16)acc2[t][reg];
    }
}

// Fused aggregation + layer-3 GEMM (48 cols) into [N+1][64]-stride buffer.
__launch_bounds__(256)
__global__ void k_fused40(const _Float16* __restrict__ hp, const i32x2* __restrict__ rowse,
                          const int* __restrict__ colidx, const float* __restrict__ bias,
                          const float* __restrict__ dinv,
                          const _Float16* __restrict__ Wthi, const _Float16* __restrict__ Wtlo,
                          _Float16* __restrict__ out) {
    __shared__ __align__(16) _Float16 As[16 * 128];
    const int lane = threadIdx.x & 63;
    const int wi = threadIdx.x >> 6;
    const int nn = lane & 15;
    const int quad = lane >> 4;
    const int r0 = blockIdx.x * 16;

    // ---- phase A ----
    {
        const int rl = wi * 4 + quad;
        const int r = r0 + rl;
        const i32x2 se = rowse[r];
        const int deg = se.y - se.x;
        int m = deg;
        m = max(m, __shfl_xor(m, 16));
        m = max(m, __shfl_xor(m, 32));
        const _Float16* hpc = hp + nn * 8;
        float accf[8] = {};
        for (int it = 0; it < m; it += 4) {
            int i0 = se.x + it;
            int s0 = colidx[i0];
            int s1 = colidx[i0 + 1];
            int s2 = colidx[i0 + 2];
            int s3 = colidx[i0 + 3];
            s0 = (it < deg) ? s0 : N_NODES;
            s1 = (it + 1 < deg) ? s1 : N_NODES;
            s2 = (it + 2 < deg) ? s2 : N_NODES;
            s3 = (it + 3 < deg) ? s3 : N_NODES;
            float d0 = dinv[s0];
            float d1 = dinv[s1];
            float d2 = dinv[s2];
            float d3 = dinv[s3];
            h8v v0 = *(const h8v*)(hpc + (size_t)s0 * 128);
            h8v v1 = *(const h8v*)(hpc + (size_t)s1 * 128);
            h8v v2 = *(const h8v*)(hpc + (size_t)s2 * 128);
            h8v v3 = *(const h8v*)(hpc + (size_t)s3 * 128);
#pragma unroll
            for (int j = 0; j < 8; j++) {
                accf[j] = fmaf(d0, (float)v0[j], accf[j]);
                accf[j] = fmaf(d1, (float)v1[j], accf[j]);
                accf[j] = fmaf(d2, (float)v2[j], accf[j]);
                accf[j] = fmaf(d3, (float)v3[j], accf[j]);
            }
        }
        h8v sv = *(const h8v*)(hpc + (size_t)r * 128);
        float dv = rsqrtf((float)(deg + 1));
        const float* bp = bias + nn * 8;
        float4 b0 = *(const float4*)bp;
        float4 b1 = *(const float4*)(bp + 4);
        float bb[8] = {b0.x, b0.y, b0.z, b0.w, b1.x, b1.y, b1.z, b1.w};
        h8v o;
#pragma unroll
        for (int j = 0; j < 8; j++) {
            float sx = accf[j] + dv * (float)sv[j];
            o[j] = (_Float16)fmaxf(fmaf(dv, sx, bb[j]), 0.f);
        }
        *(h8v*)(As + rl * 128 + ((nn ^ rl) * 8)) = o;
    }
    __syncthreads();

    // ---- phase B: 16x128 tile @ W3 (waves 0..2 -> cols wi*16..+15) ----
    if (wi < 3) {
        const int kq = quad * 8;
        f32x4 acc2 = {};
#pragma unroll
        for (int c = 0; c < 4; c++) {
            int ch = (c * 4 + quad) ^ nn;
            h8v a = *(const h8v*)(As + nn * 128 + ch * 8);
            int off = (wi * 16 + nn) * 128 + c * 32 + kq;
            h8v bhv = *(const h8v*)(Wthi + off);
            h8v blv = *(const h8v*)(Wtlo + off);
            acc2 = __builtin_amdgcn_mfma_f32_16x16x32_f16(a, bhv, acc2, 0, 0, 0);
            acc2 = __builtin_amdgcn_mfma_f32_16x16x32_f16(a, blv, acc2, 0, 0, 0);
        }
#pragma unroll
        for (int reg = 0; reg < 4; reg++) {
            int r = r0 + quad * 4 + reg;
            out[(size_t)r * 64 + wi * 16 + nn] = (_Float16)acc2[reg];
        }
    }
}

// ---------------- Final aggregation (64-stride rows) + fused log_softmax ----------------

__launch_bounds__(256)
__global__ void k_agg_out(const _Float16* __restrict__ hp, const i32x2* __restrict__ rowse,
                          const int* __restrict__ colidx, const float* __restrict__ dinv,
                          float* __restrict__ out) {
    const int lane = threadIdx.x & 63;
    const int wid = (blockIdx.x * blockDim.x + threadIdx.x) >> 6;
    const int rs = lane >> 3;   // row slot 0..7
    const int cp = lane & 7;    // 16B col part
    const int r = wid * 8 + rs;

    const i32x2 se = rowse[r];
    const int deg = se.y - se.x;
    int m = deg;
    m = max(m, __shfl_xor(m, 8));
    m = max(m, __shfl_xor(m, 16));
    m = max(m, __shfl_xor(m, 32));

    const _Float16* hpc = hp + cp * 8;
    float accf[8] = {};
    for (int it = 0; it < m; it += 4) {
        int i0 = se.x + it;
        int s0 = colidx[i0];
        int s1 = colidx[i0 + 1];
        int s2 = colidx[i0 + 2];
        int s3 = colidx[i0 + 3];
        s0 = (it < deg) ? s0 : N_NODES;
        s1 = (it + 1 < deg) ? s1 : N_NODES;
        s2 = (it + 2 < deg) ? s2 : N_NODES;
        s3 = (it + 3 < deg) ? s3 : N_NODES;
        float d0 = dinv[s0];
        float d1 = dinv[s1];
        float d2 = dinv[s2];
        float d3 = dinv[s3];
        h8v v0 = *(const h8v*)(hpc + (size_t)s0 * 64);
        h8v v1 = *(const h8v*)(hpc + (size_t)s1 * 64);
        h8v v2 = *(const h8v*)(hpc + (size_t)s2 * 64);
        h8v v3 = *(const h8v*)(hpc + (size_t)s3 * 64);
#pragma unroll
        for (int j = 0; j < 8; j++) {
            accf[j] = fmaf(d0, (float)v0[j], accf[j]);
            accf[j] = fmaf(d1, (float)v1[j], accf[j]);
            accf[j] = fmaf(d2, (float)v2[j], accf[j]);
            accf[j] = fmaf(d3, (float)v3[j], accf[j]);
        }
    }

    h8v sv = *(const h8v*)(hpc + (size_t)r * 64);  // self-loop (unscaled)
    float dv = rsqrtf((float)(deg + 1));
    float z[8];
#pragma unroll
    for (int j = 0; j < 8; j++) z[j] = dv * (accf[j] + dv * (float)sv[j]);

    const bool act = cp < 5;  // cols 0..39
    float pm = -INFINITY;
    if (act) {
#pragma unroll
        for (int j = 0; j < 8; j++) pm = fmaxf(pm, z[j]);
    }
    pm = fmaxf(pm, __shfl_xor(pm, 1));
    pm = fmaxf(pm, __shfl_xor(pm, 2));
    pm = fmaxf(pm, __shfl_xor(pm, 4));
    float pe = 0.f;
    if (act) {
#pragma unroll
        for (int j = 0; j < 8; j++) pe += __expf(z[j] - pm);
    }
    pe += __shfl_xor(pe, 1);
    pe += __shfl_xor(pe, 2);
    pe += __shfl_xor(pe, 4);
    float lse = __logf(pe);
    if (act) {
        float* po = out + (size_t)r * 40 + cp * 8;
        float4 o0 = make_float4(z[0] - pm - lse, z[1] - pm - lse, z[2] - pm - lse, z[3] - pm - lse);
        float4 o1 = make_float4(z[4] - pm - lse, z[5] - pm - lse, z[6] - pm - lse, z[7] - pm - lse);
        *(float4*)po = o0;
        *(float4*)(po + 4) = o1;
    }
}

// ---------------- launch ----------------

extern "C" void kernel_launch(void* const* d_in, const int* in_sizes, int n_in,
                              void* d_out, int out_size, void* d_ws, size_t ws_size,
                              hipStream_t stream) {
    const float* x     = (const float*)d_in[0];
    const int*   ei    = (const int*)d_in[1];
    const float* W_in  = (const float*)d_in[2];
    const float* b_in  = (const float*)d_in[3];
    const float* W_mid = (const float*)d_in[4];
    const float* b_mid = (const float*)d_in[5];
    const float* W_out = (const float*)d_in[6];
    float* out = (float*)d_out;

    const int* srcv = ei;
    const int* dstv = ei + N_EDGES;

    char* w = (char*)d_ws;
    float* dinv   = (float*)(w);                              // 400 KB (+ sentinel)
    i32x2* rowse  = (i32x2*)(w + (1ull << 19));               // 800 KB
    int* bcnt     = (int*)(w + 1507328);                      // 2 KB
    int* colidx   = (int*)(w + (2ull << 20));                 // 7.2 MB + pad
    unsigned int* ebuf = (unsigned int*)(w + (10ull << 20));  // 7.2 MB
    _Float16* Wt  = (_Float16*)(w + (18ull << 20));           // 155 KB
    _Float16* bufA = (_Float16*)(w + (19ull << 20));          // (N+1)*128 fp16
    _Float16* bufB = (_Float16*)(w + (45ull << 20));          // (N+1)*128 fp16
    _Float16* zbuf = (_Float16*)(w + (71ull << 20));          // (N+1)*64 fp16

    _Float16* W2h = Wt + 2 * 128 * 128;
    _Float16* W2l = Wt + 3 * 128 * 128;
    _Float16* W3h = Wt + 4 * 128 * 128;
    _Float16* W3l = Wt + 4 * 128 * 128 + 48 * 128;

    // mega-prep: L1 GEMM (0..624) + bpart (625..1015) + wprep (1016..1103) + zrows (1104)
    (void)hipMemsetAsync(bcnt, 0, NBUCK * sizeof(int), stream);
    k_prep<<<1105, 256, 0, stream>>>(srcv, dstv, bcnt, ebuf, x, W_in, W_mid, W_out,
                                     Wt, bufA, bufB, zbuf);
    k_bucket<<<NBUCK, 256, 0, stream>>>(ebuf, bcnt, rowse, dinv, colidx);

    // Layer 1 agg (+bias+relu) + Layer 2 GEMM fused: gather bufA -> @W2 -> bufB
    k_fused128<<<N_NODES / 16, 256, 0, stream>>>(bufA, rowse, colidx, b_in, dinv, W2h, W2l, bufB);
    // Layer 2 agg (+bias+relu) + Layer 3 GEMM fused: gather bufB -> @W3 -> zbuf
    k_fused40<<<N_NODES / 16, 256, 0, stream>>>(bufB, rowse, colidx, b_mid, dinv, W3h, W3l, zbuf);
    // Final aggregation + log_softmax
    k_agg_out<<<N_NODES / 32, 256, 0, stream>>>(zbuf, rowse, colidx, dinv, out);
}